// Round 11
// baseline (55373.065 us; speedup 1.0000x reference)
//
#include <hip/hip_runtime.h>
#include <stdint.h>

#define T_STEPS 25
#define BATCH   1024
#define IN_F    784
#define HID     4096
#define OUTF    10
// Eigen SINGLE-THREADED gebp blocking (scan-body dots can't use the intra-op
// pool): max_kc=288 (AVX traits, 32KB L1), then "evened" so the last block
// stays large:  kc(784)=264 (264+264+256), kc(4096)=280 (14x280+176).
#define KC_L0   264
#define KC_L1   280

// ---------------- Threefry-2x32, key = (0, 42), 20 rounds ----------------
__device__ __forceinline__ uint32_t rotl32(uint32_t x, int d) {
    return (x << d) | (x >> (32 - d));
}

__device__ __forceinline__ void threefry2x32_42(uint32_t x0, uint32_t x1,
                                                uint32_t& r0, uint32_t& r1) {
    const uint32_t k0 = 0u, k1 = 42u;
    const uint32_t k2 = k0 ^ k1 ^ 0x1BD11BDAu;
    x0 += k0; x1 += k1;
#define TF_ROUND(r) { x0 += x1; x1 = rotl32(x1, r); x1 ^= x0; }
    TF_ROUND(13) TF_ROUND(15) TF_ROUND(26) TF_ROUND(6)
    x0 += k1; x1 += k2 + 1u;
    TF_ROUND(17) TF_ROUND(29) TF_ROUND(16) TF_ROUND(24)
    x0 += k2; x1 += k0 + 2u;
    TF_ROUND(13) TF_ROUND(15) TF_ROUND(26) TF_ROUND(6)
    x0 += k0; x1 += k1 + 3u;
    TF_ROUND(17) TF_ROUND(29) TF_ROUND(16) TF_ROUND(24)
    x0 += k1; x1 += k2 + 4u;
    TF_ROUND(13) TF_ROUND(15) TF_ROUND(26) TF_ROUND(6)
    x0 += k2; x1 += k0 + 5u;
#undef TF_ROUND
    r0 = x0; r1 = x1;
}

// ---------------- Input spike generation (bitmask, ballot) ----------------
// JAX partitionable readout (verified): bits = x1 ^ x2, counter = (0, i).
// Sin layout: [T][B][16] uint64 (784 bits used).
__global__ __launch_bounds__(256) void gen_spikes(const float* __restrict__ x,
                                                  uint64_t* __restrict__ Sin) {
    const int lane = threadIdx.x & 63;
    const int wid  = __builtin_amdgcn_readfirstlane(blockIdx.x * 4 + (threadIdx.x >> 6));
    if (wid >= T_STEPS * BATCH) return;
    const int b = wid % BATCH;

    for (int qw = 0; qw < 16; ++qw) {
        bool pred = false;
        const int f = qw * 64 + lane;
        if (f < IN_F) {
            const uint32_t i = (uint32_t)(wid * IN_F + f);
            uint32_t r0, r1;
            threefry2x32_42(0u, i, r0, r1);
            const uint32_t bits = r0 ^ r1;
            const uint32_t fbits = (bits >> 9) | 0x3f800000u;
            const float u = __uint_as_float(fbits) - 1.0f;
            float p = x[b * IN_F + f];
            p = fminf(fmaxf(p, 0.0f), 1.0f);
            pred = (u < p);
        }
        const uint64_t mask = __ballot((int)pred);
        if (lane == 0) Sin[(long long)wid * 16 + qw] = mask;
    }
}

// ---------------- Weight transpose: WT[f*H + h] = W[h*F + f] ----------------
__global__ __launch_bounds__(256) void transpose_w(const float* __restrict__ W,
                                                   float* __restrict__ WT,
                                                   int H, int F) {
    const long long idx = (long long)blockIdx.x * blockDim.x + threadIdx.x;
    const long long tot = (long long)H * F;
    if (idx >= tot) return;
    const long long f = idx / H;
    const long long h = idx % H;
    WT[idx] = W[h * (long long)F + f];
}

// ---------------- Fused layer: f32 KC-blocked dot + strict f32 LIF --------
// Single-threaded Eigen gebp emulation: K split into KC blocks (evened
// heuristic, fold at arbitrary global-k positions); within a block one f32
// accumulator per C element, ascending k (mul/fma with 0/1 spike == exact
// conditional add); block partials folded sequentially into C (starts at 0).
template<int KCB, int FQW_STRIDE, int FQW_USED, int FVALID, int HQW>
__global__ __launch_bounds__(256) void layer_fused(const uint64_t* __restrict__ Sin,
                                                   const float* __restrict__ WT,
                                                   uint64_t* __restrict__ Sout) {
    const int lane = threadIdx.x & 63;
    const int wid  = __builtin_amdgcn_readfirstlane(blockIdx.x * 4 + (threadIdx.x >> 6));
    const int b  = wid / HQW;
    const int hq = wid % HQW;
    if (b >= BATCH) return;
    const int h  = hq * 64 + lane;
    const int HH = HQW * 64;

    float acc[T_STEPS];   // folded block partials (the gemm C value)
    float S[T_STEPS];     // current KC-block partial
#pragma unroll
    for (int t = 0; t < T_STEPS; ++t) { acc[t] = 0.0f; S[t] = 0.0f; }

    for (int qw = 0; qw < FQW_USED; ++qw) {
        uint64_t sw[T_STEPS];
#pragma unroll
        for (int t = 0; t < T_STEPS; ++t)
            sw[t] = Sin[((long long)t * BATCH + b) * FQW_STRIDE + qw];

        int fb_max = FVALID - qw * 64;
        if (fb_max > 64) fb_max = 64;
        for (int fb = 0; fb < fb_max; ++fb) {
            const float w = WT[(long long)(qw * 64 + fb) * HH + h];
#pragma unroll
            for (int t = 0; t < T_STEPS; ++t) {
                S[t] = __fadd_rn(S[t], ((sw[t] >> fb) & 1ull) ? w : 0.0f);
            }
            // KC-block boundary (any alignment): fold partial into acc
            if (((qw * 64 + fb + 1) % KCB) == 0) {
#pragma unroll
                for (int t = 0; t < T_STEPS; ++t) {
                    acc[t] = __fadd_rn(acc[t], S[t]);
                    S[t] = 0.0f;
                }
            }
        }
    }
    // tail fold (compile-time: only if K not a multiple of KC)
    if (FVALID % KCB != 0) {
#pragma unroll
        for (int t = 0; t < T_STEPS; ++t) acc[t] = __fadd_rn(acc[t], S[t]);
    }

    // LIF recursion, strict f32 separate roundings (XLA elementwise: no FMA)
    float m = 0.0f;
#pragma unroll
    for (int t = 0; t < T_STEPS; ++t) {
        const float reset = (m > 1.0f) ? 1.0f : 0.0f;
        m = __fsub_rn(__fadd_rn(__fmul_rn(0.9f, m), acc[t]), reset);
        const uint64_t mask = __ballot((int)(m > 1.0f));
        if (lane == 0) Sout[((long long)t * BATCH + b) * HQW + hq] = mask;
    }
}

// ---------------- Output layer (H=10): counts, same blocked f32 (kc=280) --
__global__ __launch_bounds__(256) void layer_out(const uint64_t* __restrict__ S1,
                                                 const float* __restrict__ W2,
                                                 float* __restrict__ out) {
    const int idx = blockIdx.x * blockDim.x + threadIdx.x;
    const int b = idx >> 4;   // 16 threads per batch row (10 used)
    const int o = idx & 15;
    if (b >= BATCH) return;

    float m = 0.0f;
    float cnt = 0.0f;
    for (int t = 0; t < T_STEPS; ++t) {
        float acc = 0.0f;
        float S = 0.0f;
        if (o < OUTF) {
            for (int qw = 0; qw < 64; ++qw) {
                const uint64_t sw = S1[((long long)t * BATCH + b) * 64 + qw];
                const float* wrow = W2 + (long long)o * HID + qw * 64;
#pragma unroll
                for (int fb = 0; fb < 64; ++fb) {
                    S = __fadd_rn(S, ((sw >> fb) & 1ull) ? wrow[fb] : 0.0f);
                    if (((qw * 64 + fb + 1) % KC_L1) == 0) {
                        acc = __fadd_rn(acc, S);
                        S = 0.0f;
                    }
                }
            }
            if (HID % KC_L1 != 0) acc = __fadd_rn(acc, S);
        }
        const float reset = (m > 1.0f) ? 1.0f : 0.0f;
        m = __fsub_rn(__fadd_rn(__fmul_rn(0.9f, m), acc), reset);
        if (m > 1.0f) cnt += 1.0f;
    }
    if (o < OUTF) out[b * OUTF + o] = cnt;
}

// ---------------- Launch ----------------
extern "C" void kernel_launch(void* const* d_in, const int* in_sizes, int n_in,
                              void* d_out, int out_size, void* d_ws, size_t ws_size,
                              hipStream_t stream) {
    const float* x  = (const float*)d_in[0];
    const float* W0 = (const float*)d_in[1];
    const float* W1 = (const float*)d_in[2];
    const float* W2 = (const float*)d_in[3];
    float* out = (float*)d_out;

    char* ws = (char*)d_ws;
    size_t off = 0;
    float* WT0 = (float*)(ws + off); off += (size_t)IN_F * HID * sizeof(float);   // 12.8 MB
    float* WT1 = (float*)(ws + off); off += (size_t)HID * HID * sizeof(float);    // 64 MB
    uint64_t* Sin = (uint64_t*)(ws + off); off += (size_t)T_STEPS * BATCH * 16 * 8; // 3.3 MB
    uint64_t* S0  = (uint64_t*)(ws + off); off += (size_t)T_STEPS * BATCH * 64 * 8; // 13.1 MB
    uint64_t* S1  = (uint64_t*)(ws + off); off += (size_t)T_STEPS * BATCH * 64 * 8; // 13.1 MB
    (void)off; (void)ws_size; (void)in_sizes; (void)n_in; (void)out_size;

    // 1) transpose weights for coalesced lane=h access
    {
        long long tot0 = (long long)HID * IN_F;
        transpose_w<<<(int)((tot0 + 255) / 256), 256, 0, stream>>>(W0, WT0, HID, IN_F);
        long long tot1 = (long long)HID * HID;
        transpose_w<<<(int)((tot1 + 255) / 256), 256, 0, stream>>>(W1, WT1, HID, HID);
    }
    // 2) Poisson spike raster via threefry (partitionable, XOR readout)
    gen_spikes<<<(T_STEPS * BATCH) / 4, 256, 0, stream>>>(x, Sin);
    // 3) layer 0: 784 -> 4096, kc=264 (264+264+256)
    layer_fused<KC_L0, 16, 13, 784, 64><<<BATCH * 64 / 4, 256, 0, stream>>>(Sin, WT0, S0);
    // 4) layer 1: 4096 -> 4096, kc=280 (14x280+176)
    layer_fused<KC_L1, 64, 64, 4096, 64><<<BATCH * 64 / 4, 256, 0, stream>>>(S0, WT1, S1);
    // 5) layer 2: 4096 -> 10, kc=280, spike counts
    layer_out<<<BATCH * 16 / 256, 256, 0, stream>>>(S1, W2, out);
}

// Round 12
// 48640.628 us; speedup vs baseline: 1.1384x; 1.1384x over previous
//
#include <hip/hip_runtime.h>
#include <stdint.h>

#define T_STEPS 25
#define BATCH   1024
#define IN_F    784
#define HID     4096
#define OUTF    10
// Eigen SINGLE-THREADED gebp blocking (verified bit-exact in R11):
// max_kc=288 evened -> kc(784)=264 (264+264+256), kc(4096)=280 (14x280+176).
#define KC_L0   264
#define KC_L1   280

// ---------------- Threefry-2x32, key = (0, 42), 20 rounds ----------------
__device__ __forceinline__ uint32_t rotl32(uint32_t x, int d) {
    return (x << d) | (x >> (32 - d));
}

__device__ __forceinline__ void threefry2x32_42(uint32_t x0, uint32_t x1,
                                                uint32_t& r0, uint32_t& r1) {
    const uint32_t k0 = 0u, k1 = 42u;
    const uint32_t k2 = k0 ^ k1 ^ 0x1BD11BDAu;
    x0 += k0; x1 += k1;
#define TF_ROUND(r) { x0 += x1; x1 = rotl32(x1, r); x1 ^= x0; }
    TF_ROUND(13) TF_ROUND(15) TF_ROUND(26) TF_ROUND(6)
    x0 += k1; x1 += k2 + 1u;
    TF_ROUND(17) TF_ROUND(29) TF_ROUND(16) TF_ROUND(24)
    x0 += k2; x1 += k0 + 2u;
    TF_ROUND(13) TF_ROUND(15) TF_ROUND(26) TF_ROUND(6)
    x0 += k0; x1 += k1 + 3u;
    TF_ROUND(17) TF_ROUND(29) TF_ROUND(16) TF_ROUND(24)
    x0 += k1; x1 += k2 + 4u;
    TF_ROUND(13) TF_ROUND(15) TF_ROUND(26) TF_ROUND(6)
    x0 += k2; x1 += k0 + 5u;
#undef TF_ROUND
    r0 = x0; r1 = x1;
}

// ---------------- Input spike generation (bitmask, ballot) ----------------
// JAX partitionable readout (verified): bits = x1 ^ x2, counter = (0, i).
// Sin layout: [T][B][16] uint64 (784 bits used).
__global__ __launch_bounds__(256) void gen_spikes(const float* __restrict__ x,
                                                  uint64_t* __restrict__ Sin) {
    const int lane = threadIdx.x & 63;
    const int wid  = __builtin_amdgcn_readfirstlane(blockIdx.x * 4 + (threadIdx.x >> 6));
    if (wid >= T_STEPS * BATCH) return;
    const int b = wid % BATCH;

    for (int qw = 0; qw < 16; ++qw) {
        bool pred = false;
        const int f = qw * 64 + lane;
        if (f < IN_F) {
            const uint32_t i = (uint32_t)(wid * IN_F + f);
            uint32_t r0, r1;
            threefry2x32_42(0u, i, r0, r1);
            const uint32_t bits = r0 ^ r1;
            const uint32_t fbits = (bits >> 9) | 0x3f800000u;
            const float u = __uint_as_float(fbits) - 1.0f;
            float p = x[b * IN_F + f];
            p = fminf(fmaxf(p, 0.0f), 1.0f);
            pred = (u < p);
        }
        const uint64_t mask = __ballot((int)pred);
        if (lane == 0) Sin[(long long)wid * 16 + qw] = mask;
    }
}

// ---------------- Weight transpose: WT[f*H + h] = W[h*F + f] ----------------
__global__ __launch_bounds__(256) void transpose_w(const float* __restrict__ W,
                                                   float* __restrict__ WT,
                                                   int H, int F) {
    const long long idx = (long long)blockIdx.x * blockDim.x + threadIdx.x;
    const long long tot = (long long)H * F;
    if (idx >= tot) return;
    const long long f = idx / H;
    const long long h = idx % H;
    WT[idx] = W[h * (long long)F + f];
}

// ---------------- Fused layer, fmac formulation ----------------
// Bit-exact to Eigen gebp: S[t] = fma(fbit, w, S[t]) where fbit in {0.0f,1.0f}
// == round(S + 1*w) or round(S + (+/-0)) — identical roundings to the golden's
// madd over ALL k (golden also processes zero spikes: S + 0*w). Folds at
// global k % KCB == 0 via scalar countdown; tail fold if KTOT % KCB != 0.
// Spike bits for a 256-k chunk are expanded once per block into an LDS tile
// of floats [256][32] shared by WPB waves (uniform ds_reads broadcast).
template<int KCB, int KTOT, int IN_STRIDE, int HTOT, int WPB>
__global__ __launch_bounds__(WPB * 64, 4) void layer_fmac(
    const uint64_t* __restrict__ Bin,   // [T][B][IN_STRIDE] u64, bit index = k
    const float*    __restrict__ WT,    // [KTOT][HTOT]
    uint64_t*       __restrict__ Bout)  // [T][B][HTOT/64]
{
    __shared__ float tile[256 * 32];    // 32 KB
    const int tid  = threadIdx.x;
    const int lane = tid & 63;
    const int wv   = tid >> 6;
    const int nhb  = HTOT / (WPB * 64);
    const int b    = blockIdx.x / nhb;
    const int hb   = blockIdx.x % nhb;
    const int h    = hb * (WPB * 64) + wv * 64 + lane;

    float S[T_STEPS], acc[T_STEPS];
#pragma unroll
    for (int t = 0; t < T_STEPS; ++t) { S[t] = 0.0f; acc[t] = 0.0f; }

    int nf = KCB;                       // next fold boundary (k+1 == nf)
    constexpr int NCH = (KTOT + 255) / 256;
#pragma unroll
    for (int c = 0; c < NCH; ++c) {
        const int k0 = c * 256;
        const int kv = (KTOT - k0 < 256) ? (KTOT - k0) : 256;
        __syncthreads();                // previous tile fully consumed
        const int NV = kv * T_STEPS;
        for (int r = 0; r < (NV + WPB * 64 - 1) / (WPB * 64); ++r) {
            const int idx = r * (WPB * 64) + tid;
            if (idx < NV) {
                const int kk = (idx * 5243) >> 17;   // idx/25 for idx<32768
                const int t  = idx - kk * 25;
                const int k  = k0 + kk;
                const uint64_t word =
                    Bin[((long long)t * BATCH + b) * IN_STRIDE + (k >> 6)];
                tile[kk * 32 + t] = ((word >> (k & 63)) & 1ull) ? 1.0f : 0.0f;
            }
        }
        __syncthreads();
        for (int kk = 0; kk < kv; ++kk) {
            const float wval = WT[(long long)(k0 + kk) * HTOT + h];
            const float* fb = &tile[kk * 32];
#pragma unroll
            for (int t = 0; t < T_STEPS; ++t)
                S[t] = fmaf(fb[t], wval, S[t]);      // 1 VALU inst per MAC
            if (k0 + kk + 1 == nf) {                  // exact KC fold boundary
#pragma unroll
                for (int t = 0; t < T_STEPS; ++t) {
                    acc[t] = __fadd_rn(acc[t], S[t]);
                    S[t] = 0.0f;
                }
                nf += KCB;
            }
        }
    }
    if (KTOT % KCB != 0) {
#pragma unroll
        for (int t = 0; t < T_STEPS; ++t) acc[t] = __fadd_rn(acc[t], S[t]);
    }

    // LIF recursion, strict f32 separate roundings (verified R11)
    float m = 0.0f;
#pragma unroll
    for (int t = 0; t < T_STEPS; ++t) {
        const float reset = (m > 1.0f) ? 1.0f : 0.0f;
        m = __fsub_rn(__fadd_rn(__fmul_rn(0.9f, m), acc[t]), reset);
        const uint64_t mask = __ballot((int)(m > 1.0f));
        if (lane == 0)
            Bout[((long long)t * BATCH + b) * (HTOT / 64) + hb * WPB + wv] = mask;
    }
}

// ---------------- Output layer (H=10): counts, blocked f32 (kc=280) -------
__global__ __launch_bounds__(256) void layer_out(const uint64_t* __restrict__ S1,
                                                 const float* __restrict__ W2,
                                                 float* __restrict__ out) {
    const int idx = blockIdx.x * blockDim.x + threadIdx.x;
    const int b = idx >> 4;   // 16 threads per batch row (10 used)
    const int o = idx & 15;
    if (b >= BATCH) return;

    float m = 0.0f;
    float cnt = 0.0f;
    for (int t = 0; t < T_STEPS; ++t) {
        float acc = 0.0f;
        float S = 0.0f;
        if (o < OUTF) {
            for (int qw = 0; qw < 64; ++qw) {
                const uint64_t sw = S1[((long long)t * BATCH + b) * 64 + qw];
                const float* wrow = W2 + (long long)o * HID + qw * 64;
#pragma unroll
                for (int fb = 0; fb < 64; ++fb) {
                    S = __fadd_rn(S, ((sw >> fb) & 1ull) ? wrow[fb] : 0.0f);
                    if (((qw * 64 + fb + 1) % KC_L1) == 0) {
                        acc = __fadd_rn(acc, S);
                        S = 0.0f;
                    }
                }
            }
            if (HID % KC_L1 != 0) acc = __fadd_rn(acc, S);
        }
        const float reset = (m > 1.0f) ? 1.0f : 0.0f;
        m = __fsub_rn(__fadd_rn(__fmul_rn(0.9f, m), acc), reset);
        if (m > 1.0f) cnt += 1.0f;
    }
    if (o < OUTF) out[b * OUTF + o] = cnt;
}

// ---------------- Launch ----------------
extern "C" void kernel_launch(void* const* d_in, const int* in_sizes, int n_in,
                              void* d_out, int out_size, void* d_ws, size_t ws_size,
                              hipStream_t stream) {
    const float* x  = (const float*)d_in[0];
    const float* W0 = (const float*)d_in[1];
    const float* W1 = (const float*)d_in[2];
    const float* W2 = (const float*)d_in[3];
    float* out = (float*)d_out;

    char* ws = (char*)d_ws;
    size_t off = 0;
    float* WT0 = (float*)(ws + off); off += (size_t)IN_F * HID * sizeof(float);   // 12.8 MB
    float* WT1 = (float*)(ws + off); off += (size_t)HID * HID * sizeof(float);    // 64 MB
    uint64_t* Sin = (uint64_t*)(ws + off); off += (size_t)T_STEPS * BATCH * 16 * 8; // 3.3 MB
    uint64_t* S0  = (uint64_t*)(ws + off); off += (size_t)T_STEPS * BATCH * 64 * 8; // 13.1 MB
    uint64_t* S1  = (uint64_t*)(ws + off); off += (size_t)T_STEPS * BATCH * 64 * 8; // 13.1 MB
    (void)off; (void)ws_size; (void)in_sizes; (void)n_in; (void)out_size;

    // 1) transpose weights for coalesced lane=h access
    {
        long long tot0 = (long long)HID * IN_F;
        transpose_w<<<(int)((tot0 + 255) / 256), 256, 0, stream>>>(W0, WT0, HID, IN_F);
        long long tot1 = (long long)HID * HID;
        transpose_w<<<(int)((tot1 + 255) / 256), 256, 0, stream>>>(W1, WT1, HID, HID);
    }
    // 2) Poisson spike raster via threefry (partitionable, XOR readout)
    gen_spikes<<<(T_STEPS * BATCH) / 4, 256, 0, stream>>>(x, Sin);
    // 3) layer 0: 784 -> 4096, kc=264
    layer_fmac<KC_L0, IN_F, 16, HID, 8>
        <<<BATCH * (HID / 512), 512, 0, stream>>>(Sin, WT0, S0);
    // 4) layer 1: 4096 -> 4096, kc=280
    layer_fmac<KC_L1, HID, 64, HID, 8>
        <<<BATCH * (HID / 512), 512, 0, stream>>>(S0, WT1, S1);
    // 5) layer 2: 4096 -> 10, kc=280, spike counts
    layer_out<<<BATCH * 16 / 256, 256, 0, stream>>>(S1, W2, out);
}

// Round 14
// 46580.936 us; speedup vs baseline: 1.1887x; 1.0442x over previous
//
#include <hip/hip_runtime.h>
#include <stdint.h>

#define T_STEPS 25
#define BATCH   1024
#define IN_F    784
#define HID     4096
#define OUTF    10
// Eigen SINGLE-THREADED gebp blocking (verified bit-exact in R11/R12):
// max_kc=288 evened -> kc(784)=264 (264+264+256), kc(4096)=280 (14x280+176).
#define KC_L0   264
#define KC_L1   280

// ---------------- Threefry-2x32, key = (0, 42), 20 rounds ----------------
__device__ __forceinline__ uint32_t rotl32(uint32_t x, int d) {
    return (x << d) | (x >> (32 - d));
}

__device__ __forceinline__ void threefry2x32_42(uint32_t x0, uint32_t x1,
                                                uint32_t& r0, uint32_t& r1) {
    const uint32_t k0 = 0u, k1 = 42u;
    const uint32_t k2 = k0 ^ k1 ^ 0x1BD11BDAu;
    x0 += k0; x1 += k1;
#define TF_ROUND(r) { x0 += x1; x1 = rotl32(x1, r); x1 ^= x0; }
    TF_ROUND(13) TF_ROUND(15) TF_ROUND(26) TF_ROUND(6)
    x0 += k1; x1 += k2 + 1u;
    TF_ROUND(17) TF_ROUND(29) TF_ROUND(16) TF_ROUND(24)
    x0 += k2; x1 += k0 + 2u;
    TF_ROUND(13) TF_ROUND(15) TF_ROUND(26) TF_ROUND(6)
    x0 += k0; x1 += k1 + 3u;
    TF_ROUND(17) TF_ROUND(29) TF_ROUND(16) TF_ROUND(24)
    x0 += k1; x1 += k2 + 4u;
    TF_ROUND(13) TF_ROUND(15) TF_ROUND(26) TF_ROUND(6)
    x0 += k2; x1 += k0 + 5u;
#undef TF_ROUND
    r0 = x0; r1 = x1;
}

// ---------------- Input spike generation (bitmask, ballot) ----------------
__global__ __launch_bounds__(256) void gen_spikes(const float* __restrict__ x,
                                                  uint64_t* __restrict__ Sin) {
    const int lane = threadIdx.x & 63;
    const int wid  = __builtin_amdgcn_readfirstlane(blockIdx.x * 4 + (threadIdx.x >> 6));
    if (wid >= T_STEPS * BATCH) return;
    const int b = wid % BATCH;

    for (int qw = 0; qw < 16; ++qw) {
        bool pred = false;
        const int f = qw * 64 + lane;
        if (f < IN_F) {
            const uint32_t i = (uint32_t)(wid * IN_F + f);
            uint32_t r0, r1;
            threefry2x32_42(0u, i, r0, r1);
            const uint32_t bits = r0 ^ r1;
            const uint32_t fbits = (bits >> 9) | 0x3f800000u;
            const float u = __uint_as_float(fbits) - 1.0f;
            float p = x[b * IN_F + f];
            p = fminf(fmaxf(p, 0.0f), 1.0f);
            pred = (u < p);
        }
        const uint64_t mask = __ballot((int)pred);
        if (lane == 0) Sin[(long long)wid * 16 + qw] = mask;
    }
}

// ---------------- Weight transpose: WT[f*H + h] = W[h*F + f] ----------------
__global__ __launch_bounds__(256) void transpose_w(const float* __restrict__ W,
                                                   float* __restrict__ WT,
                                                   int H, int F) {
    const long long idx = (long long)blockIdx.x * blockDim.x + threadIdx.x;
    const long long tot = (long long)H * F;
    if (idx >= tot) return;
    const long long f = idx / H;
    const long long h = idx % H;
    WT[idx] = W[h * (long long)F + f];
}

// ---------------- Fused layer, fmac + wide-LDS reads ----------------
// Bit-exact to Eigen gebp (verified R11/R12): S[t] = fmaf(fbit, w, S[t]),
// k ascending, folds at global k % KCB == 0 (scalar countdown), tail fold.
// CHANGE vs R12 (bisect round): tile stride 32 -> 28 + float4 LDS reads
// (6 x ds_read_b128 + 1 x ds_read_b32 per k, uniform-address broadcast)
// and __launch_bounds__(.,2) to stop the 274MB scratch spill. Weight path
// (transpose_w layout + scalar per-k load) kept VERBATIM from R12.
template<int KCB, int KTOT, int IN_STRIDE, int HTOT, int WPB>
__global__ __launch_bounds__(WPB * 64, 2) void layer_fmac(
    const uint64_t* __restrict__ Bin,   // [T][B][IN_STRIDE] u64, bit index = k
    const float*    __restrict__ WT,    // [KTOT][HTOT]
    uint64_t*       __restrict__ Bout)  // [T][B][HTOT/64]
{
    __shared__ alignas(16) float tile[256 * 28];    // 28 KB
    const int tid  = threadIdx.x;
    const int lane = tid & 63;
    const int wv   = tid >> 6;
    const int nhb  = HTOT / (WPB * 64);
    const int b    = blockIdx.x / nhb;
    const int hb   = blockIdx.x % nhb;
    const int h    = hb * (WPB * 64) + wv * 64 + lane;

    float S[T_STEPS], acc[T_STEPS];
#pragma unroll
    for (int t = 0; t < T_STEPS; ++t) { S[t] = 0.0f; acc[t] = 0.0f; }

    int nf = KCB;                       // next fold boundary (k+1 == nf)
    constexpr int NCH = (KTOT + 255) / 256;
#pragma unroll
    for (int c = 0; c < NCH; ++c) {
        const int k0 = c * 256;
        const int kv = (KTOT - k0 < 256) ? (KTOT - k0) : 256;
        __syncthreads();                // previous tile fully consumed
        const int NV = kv * T_STEPS;
        for (int r = 0; r < (NV + WPB * 64 - 1) / (WPB * 64); ++r) {
            const int idx = r * (WPB * 64) + tid;
            if (idx < NV) {
                const int kk = (idx * 5243) >> 17;   // idx/25, exact < 43690
                const int t  = idx - kk * 25;
                const int k  = k0 + kk;
                const uint64_t word =
                    Bin[((long long)t * BATCH + b) * IN_STRIDE + (k >> 6)];
                tile[kk * 28 + t] = ((word >> (k & 63)) & 1ull) ? 1.0f : 0.0f;
            }
        }
        __syncthreads();

        for (int kk = 0; kk < kv; ++kk) {
            const float w = WT[(long long)(k0 + kk) * HTOT + h];  // R12 path
            const float* fb = &tile[kk * 28];
            const float4 f0 = *(const float4*)(fb);
            const float4 f1 = *(const float4*)(fb + 4);
            const float4 f2 = *(const float4*)(fb + 8);
            const float4 f3 = *(const float4*)(fb + 12);
            const float4 f4 = *(const float4*)(fb + 16);
            const float4 f5 = *(const float4*)(fb + 20);
            const float  f24 = fb[24];
            S[0]  = fmaf(f0.x, w, S[0]);   S[1]  = fmaf(f0.y, w, S[1]);
            S[2]  = fmaf(f0.z, w, S[2]);   S[3]  = fmaf(f0.w, w, S[3]);
            S[4]  = fmaf(f1.x, w, S[4]);   S[5]  = fmaf(f1.y, w, S[5]);
            S[6]  = fmaf(f1.z, w, S[6]);   S[7]  = fmaf(f1.w, w, S[7]);
            S[8]  = fmaf(f2.x, w, S[8]);   S[9]  = fmaf(f2.y, w, S[9]);
            S[10] = fmaf(f2.z, w, S[10]);  S[11] = fmaf(f2.w, w, S[11]);
            S[12] = fmaf(f3.x, w, S[12]);  S[13] = fmaf(f3.y, w, S[13]);
            S[14] = fmaf(f3.z, w, S[14]);  S[15] = fmaf(f3.w, w, S[15]);
            S[16] = fmaf(f4.x, w, S[16]);  S[17] = fmaf(f4.y, w, S[17]);
            S[18] = fmaf(f4.z, w, S[18]);  S[19] = fmaf(f4.w, w, S[19]);
            S[20] = fmaf(f5.x, w, S[20]);  S[21] = fmaf(f5.y, w, S[21]);
            S[22] = fmaf(f5.z, w, S[22]);  S[23] = fmaf(f5.w, w, S[23]);
            S[24] = fmaf(f24,  w, S[24]);
            if (k0 + kk + 1 == nf) {                  // exact KC fold boundary
#pragma unroll
                for (int t = 0; t < T_STEPS; ++t) {
                    acc[t] = __fadd_rn(acc[t], S[t]);
                    S[t] = 0.0f;
                }
                nf += KCB;
            }
        }
    }
    if (KTOT % KCB != 0) {
#pragma unroll
        for (int t = 0; t < T_STEPS; ++t) acc[t] = __fadd_rn(acc[t], S[t]);
    }

    // LIF recursion, strict f32 separate roundings (verified R11)
    float m = 0.0f;
#pragma unroll
    for (int t = 0; t < T_STEPS; ++t) {
        const float reset = (m > 1.0f) ? 1.0f : 0.0f;
        m = __fsub_rn(__fadd_rn(__fmul_rn(0.9f, m), acc[t]), reset);
        const uint64_t mask = __ballot((int)(m > 1.0f));
        if (lane == 0)
            Bout[((long long)t * BATCH + b) * (HTOT / 64) + hb * WPB + wv] = mask;
    }
}

// ---------------- Output layer (H=10): counts, blocked f32 (kc=280) -------
__global__ __launch_bounds__(256) void layer_out(const uint64_t* __restrict__ S1,
                                                 const float* __restrict__ W2,
                                                 float* __restrict__ out) {
    const int idx = blockIdx.x * blockDim.x + threadIdx.x;
    const int b = idx >> 4;   // 16 threads per batch row (10 used)
    const int o = idx & 15;
    if (b >= BATCH) return;

    float m = 0.0f;
    float cnt = 0.0f;
    for (int t = 0; t < T_STEPS; ++t) {
        float acc = 0.0f;
        float S = 0.0f;
        if (o < OUTF) {
            for (int qw = 0; qw < 64; ++qw) {
                const uint64_t sw = S1[((long long)t * BATCH + b) * 64 + qw];
                const float* wrow = W2 + (long long)o * HID + qw * 64;
#pragma unroll
                for (int fb = 0; fb < 64; ++fb) {
                    S = __fadd_rn(S, ((sw >> fb) & 1ull) ? wrow[fb] : 0.0f);
                    if (((qw * 64 + fb + 1) % KC_L1) == 0) {
                        acc = __fadd_rn(acc, S);
                        S = 0.0f;
                    }
                }
            }
            if (HID % KC_L1 != 0) acc = __fadd_rn(acc, S);
        }
        const float reset = (m > 1.0f) ? 1.0f : 0.0f;
        m = __fsub_rn(__fadd_rn(__fmul_rn(0.9f, m), acc), reset);
        if (m > 1.0f) cnt += 1.0f;
    }
    if (o < OUTF) out[b * OUTF + o] = cnt;
}

// ---------------- Launch ----------------
extern "C" void kernel_launch(void* const* d_in, const int* in_sizes, int n_in,
                              void* d_out, int out_size, void* d_ws, size_t ws_size,
                              hipStream_t stream) {
    const float* x  = (const float*)d_in[0];
    const float* W0 = (const float*)d_in[1];
    const float* W1 = (const float*)d_in[2];
    const float* W2 = (const float*)d_in[3];
    float* out = (float*)d_out;

    char* ws = (char*)d_ws;
    size_t off = 0;
    float* WT0 = (float*)(ws + off); off += (size_t)IN_F * HID * sizeof(float);   // 12.8 MB
    float* WT1 = (float*)(ws + off); off += (size_t)HID * HID * sizeof(float);    // 64 MB
    uint64_t* Sin = (uint64_t*)(ws + off); off += (size_t)T_STEPS * BATCH * 16 * 8; // 3.3 MB
    uint64_t* S0  = (uint64_t*)(ws + off); off += (size_t)T_STEPS * BATCH * 64 * 8; // 13.1 MB
    uint64_t* S1  = (uint64_t*)(ws + off); off += (size_t)T_STEPS * BATCH * 64 * 8; // 13.1 MB
    (void)off; (void)ws_size; (void)in_sizes; (void)n_in; (void)out_size;

    // 1) transpose weights (R12-verbatim layout)
    {
        long long tot0 = (long long)HID * IN_F;
        transpose_w<<<(int)((tot0 + 255) / 256), 256, 0, stream>>>(W0, WT0, HID, IN_F);
        long long tot1 = (long long)HID * HID;
        transpose_w<<<(int)((tot1 + 255) / 256), 256, 0, stream>>>(W1, WT1, HID, HID);
    }
    // 2) Poisson spike raster via threefry (partitionable, XOR readout)
    gen_spikes<<<(T_STEPS * BATCH) / 4, 256, 0, stream>>>(x, Sin);
    // 3) layer 0: 784 -> 4096, kc=264
    layer_fmac<KC_L0, IN_F, 16, HID, 8>
        <<<BATCH * (HID / 512), 512, 0, stream>>>(Sin, WT0, S0);
    // 4) layer 1: 4096 -> 4096, kc=280
    layer_fmac<KC_L1, HID, 64, HID, 8>
        <<<BATCH * (HID / 512), 512, 0, stream>>>(S0, WT1, S1);
    // 5) layer 2: 4096 -> 10, kc=280, spike counts
    layer_out<<<BATCH * 16 / 256, 256, 0, stream>>>(S1, W2, out);
}

// Round 15
// 20956.546 us; speedup vs baseline: 2.6423x; 2.2227x over previous
//
#include <hip/hip_runtime.h>
#include <stdint.h>

#define T_STEPS 25
#define BATCH   1024
#define IN_F    784
#define HID     4096
#define OUTF    10
// Eigen SINGLE-THREADED gebp blocking (verified bit-exact in R11/R12/R14):
// max_kc=288 evened -> kc(784)=264 (264+264+256), kc(4096)=280 (14x280+176).
#define KC_L0   264
#define KC_L1   280

// ---------------- Threefry-2x32, key = (0, 42), 20 rounds ----------------
__device__ __forceinline__ uint32_t rotl32(uint32_t x, int d) {
    return (x << d) | (x >> (32 - d));
}

__device__ __forceinline__ void threefry2x32_42(uint32_t x0, uint32_t x1,
                                                uint32_t& r0, uint32_t& r1) {
    const uint32_t k0 = 0u, k1 = 42u;
    const uint32_t k2 = k0 ^ k1 ^ 0x1BD11BDAu;
    x0 += k0; x1 += k1;
#define TF_ROUND(r) { x0 += x1; x1 = rotl32(x1, r); x1 ^= x0; }
    TF_ROUND(13) TF_ROUND(15) TF_ROUND(26) TF_ROUND(6)
    x0 += k1; x1 += k2 + 1u;
    TF_ROUND(17) TF_ROUND(29) TF_ROUND(16) TF_ROUND(24)
    x0 += k2; x1 += k0 + 2u;
    TF_ROUND(13) TF_ROUND(15) TF_ROUND(26) TF_ROUND(6)
    x0 += k0; x1 += k1 + 3u;
    TF_ROUND(17) TF_ROUND(29) TF_ROUND(16) TF_ROUND(24)
    x0 += k1; x1 += k2 + 4u;
    TF_ROUND(13) TF_ROUND(15) TF_ROUND(26) TF_ROUND(6)
    x0 += k2; x1 += k0 + 5u;
#undef TF_ROUND
    r0 = x0; r1 = x1;
}

// ---------------- Input spike generation (bitmask, ballot) ----------------
__global__ __launch_bounds__(256) void gen_spikes(const float* __restrict__ x,
                                                  uint64_t* __restrict__ Sin) {
    const int lane = threadIdx.x & 63;
    const int wid  = __builtin_amdgcn_readfirstlane(blockIdx.x * 4 + (threadIdx.x >> 6));
    if (wid >= T_STEPS * BATCH) return;
    const int b = wid % BATCH;

    for (int qw = 0; qw < 16; ++qw) {
        bool pred = false;
        const int f = qw * 64 + lane;
        if (f < IN_F) {
            const uint32_t i = (uint32_t)(wid * IN_F + f);
            uint32_t r0, r1;
            threefry2x32_42(0u, i, r0, r1);
            const uint32_t bits = r0 ^ r1;
            const uint32_t fbits = (bits >> 9) | 0x3f800000u;
            const float u = __uint_as_float(fbits) - 1.0f;
            float p = x[b * IN_F + f];
            p = fminf(fmaxf(p, 0.0f), 1.0f);
            pred = (u < p);
        }
        const uint64_t mask = __ballot((int)pred);
        if (lane == 0) Sin[(long long)wid * 16 + qw] = mask;
    }
}

// ---------------- Weight transpose: WT[f*H + h] = W[h*F + f] ----------------
__global__ __launch_bounds__(256) void transpose_w(const float* __restrict__ W,
                                                   float* __restrict__ WT,
                                                   int H, int F) {
    const long long idx = (long long)blockIdx.x * blockDim.x + threadIdx.x;
    const long long tot = (long long)H * F;
    if (idx >= tot) return;
    const long long f = idx / H;
    const long long h = idx % H;
    WT[idx] = W[h * (long long)F + f];
}

// ---------------- Fused layer: 2 h-columns/thread, fmac + wide LDS --------
// Bit-exact to Eigen gebp (verified R11/R12/R14): S[t] = fmaf(fbit, w, S[t]),
// k ascending, folds at global k % KCB == 0, tail fold. Each thread owns
// h = ha (lane) and ha+64 — ballot packs each 64-h word naturally. The 7
// uniform LDS spike reads per k now feed 50 FMAs; 2 coalesced dword weight
// loads per k with next-k register prefetch. 256-thread blocks, VGPR<=128
// (4 blocks/CU = 16 waves/CU).
template<int KCB, int KTOT, int IN_STRIDE, int HTOT, int WPB>
__global__ __launch_bounds__(WPB * 64, 4) void layer_fmac(
    const uint64_t* __restrict__ Bin,   // [T][B][IN_STRIDE] u64, bit index = k
    const float*    __restrict__ WT,    // [KTOT][HTOT]
    uint64_t*       __restrict__ Bout)  // [T][B][HTOT/64]
{
    __shared__ alignas(16) float tile[256 * 28];    // 28 KB
    const int tid  = threadIdx.x;
    const int lane = tid & 63;
    const int wv   = tid >> 6;
    const int nhb  = HTOT / (WPB * 128);            // 128 h per wave
    const int b    = blockIdx.x / nhb;
    const int hb   = blockIdx.x % nhb;              // == XCD id when nhb==8
    const int ha   = hb * (WPB * 128) + wv * 128 + lane;
    const int hc   = ha + 64;

    float Sa[T_STEPS], Sb[T_STEPS], Aa[T_STEPS], Ab[T_STEPS];
#pragma unroll
    for (int t = 0; t < T_STEPS; ++t) { Sa[t] = 0.0f; Sb[t] = 0.0f;
                                        Aa[t] = 0.0f; Ab[t] = 0.0f; }

    int nf = KCB;                       // next fold boundary (k+1 == nf)
    const int NCH = (KTOT + 255) / 256;
    for (int c = 0; c < NCH; ++c) {
        const int k0 = c * 256;
        const int kv = (KTOT - k0 < 256) ? (KTOT - k0) : 256;
        __syncthreads();                // previous tile fully consumed
        const int NV = kv * T_STEPS;
        for (int r = 0; r < (NV + WPB * 64 - 1) / (WPB * 64); ++r) {
            const int idx = r * (WPB * 64) + tid;
            if (idx < NV) {
                const int kk = (idx * 5243) >> 17;   // idx/25, exact < 43690
                const int t  = idx - kk * 25;
                const int k  = k0 + kk;
                const uint64_t word =
                    Bin[((long long)t * BATCH + b) * IN_STRIDE + (k >> 6)];
                tile[kk * 28 + t] = ((word >> (k & 63)) & 1ull) ? 1.0f : 0.0f;
            }
        }
        __syncthreads();

        float wa = WT[(long long)k0 * HTOT + ha];
        float wb = WT[(long long)k0 * HTOT + hc];
        for (int kk = 0; kk < kv; ++kk) {
            float wan = wa, wbn = wb;
            if (kk + 1 < kv) {          // next-k register prefetch
                wan = WT[(long long)(k0 + kk + 1) * HTOT + ha];
                wbn = WT[(long long)(k0 + kk + 1) * HTOT + hc];
            }
            const float* fb = &tile[kk * 28];
            {   const float4 f = *(const float4*)(fb);
                Sa[0]=fmaf(f.x,wa,Sa[0]); Sa[1]=fmaf(f.y,wa,Sa[1]);
                Sa[2]=fmaf(f.z,wa,Sa[2]); Sa[3]=fmaf(f.w,wa,Sa[3]);
                Sb[0]=fmaf(f.x,wb,Sb[0]); Sb[1]=fmaf(f.y,wb,Sb[1]);
                Sb[2]=fmaf(f.z,wb,Sb[2]); Sb[3]=fmaf(f.w,wb,Sb[3]); }
            {   const float4 f = *(const float4*)(fb + 4);
                Sa[4]=fmaf(f.x,wa,Sa[4]); Sa[5]=fmaf(f.y,wa,Sa[5]);
                Sa[6]=fmaf(f.z,wa,Sa[6]); Sa[7]=fmaf(f.w,wa,Sa[7]);
                Sb[4]=fmaf(f.x,wb,Sb[4]); Sb[5]=fmaf(f.y,wb,Sb[5]);
                Sb[6]=fmaf(f.z,wb,Sb[6]); Sb[7]=fmaf(f.w,wb,Sb[7]); }
            {   const float4 f = *(const float4*)(fb + 8);
                Sa[8]=fmaf(f.x,wa,Sa[8]);   Sa[9]=fmaf(f.y,wa,Sa[9]);
                Sa[10]=fmaf(f.z,wa,Sa[10]); Sa[11]=fmaf(f.w,wa,Sa[11]);
                Sb[8]=fmaf(f.x,wb,Sb[8]);   Sb[9]=fmaf(f.y,wb,Sb[9]);
                Sb[10]=fmaf(f.z,wb,Sb[10]); Sb[11]=fmaf(f.w,wb,Sb[11]); }
            {   const float4 f = *(const float4*)(fb + 12);
                Sa[12]=fmaf(f.x,wa,Sa[12]); Sa[13]=fmaf(f.y,wa,Sa[13]);
                Sa[14]=fmaf(f.z,wa,Sa[14]); Sa[15]=fmaf(f.w,wa,Sa[15]);
                Sb[12]=fmaf(f.x,wb,Sb[12]); Sb[13]=fmaf(f.y,wb,Sb[13]);
                Sb[14]=fmaf(f.z,wb,Sb[14]); Sb[15]=fmaf(f.w,wb,Sb[15]); }
            {   const float4 f = *(const float4*)(fb + 16);
                Sa[16]=fmaf(f.x,wa,Sa[16]); Sa[17]=fmaf(f.y,wa,Sa[17]);
                Sa[18]=fmaf(f.z,wa,Sa[18]); Sa[19]=fmaf(f.w,wa,Sa[19]);
                Sb[16]=fmaf(f.x,wb,Sb[16]); Sb[17]=fmaf(f.y,wb,Sb[17]);
                Sb[18]=fmaf(f.z,wb,Sb[18]); Sb[19]=fmaf(f.w,wb,Sb[19]); }
            {   const float4 f = *(const float4*)(fb + 20);
                Sa[20]=fmaf(f.x,wa,Sa[20]); Sa[21]=fmaf(f.y,wa,Sa[21]);
                Sa[22]=fmaf(f.z,wa,Sa[22]); Sa[23]=fmaf(f.w,wa,Sa[23]);
                Sb[20]=fmaf(f.x,wb,Sb[20]); Sb[21]=fmaf(f.y,wb,Sb[21]);
                Sb[22]=fmaf(f.z,wb,Sb[22]); Sb[23]=fmaf(f.w,wb,Sb[23]); }
            {   const float f24 = fb[24];
                Sa[24]=fmaf(f24,wa,Sa[24]); Sb[24]=fmaf(f24,wb,Sb[24]); }
            if (k0 + kk + 1 == nf) {                  // exact KC fold boundary
#pragma unroll
                for (int t = 0; t < T_STEPS; ++t) {
                    Aa[t] = __fadd_rn(Aa[t], Sa[t]);  Sa[t] = 0.0f;
                    Ab[t] = __fadd_rn(Ab[t], Sb[t]);  Sb[t] = 0.0f;
                }
                nf += KCB;
            }
            wa = wan; wb = wbn;
        }
    }
    if (KTOT % KCB != 0) {
#pragma unroll
        for (int t = 0; t < T_STEPS; ++t) {
            Aa[t] = __fadd_rn(Aa[t], Sa[t]);
            Ab[t] = __fadd_rn(Ab[t], Sb[t]);
        }
    }

    // LIF recursion x2, strict f32 separate roundings (verified R11)
    float ma = 0.0f, mb = 0.0f;
    const long long wbase = hb * (WPB * 2) + wv * 2;
#pragma unroll
    for (int t = 0; t < T_STEPS; ++t) {
        const float ra = (ma > 1.0f) ? 1.0f : 0.0f;
        ma = __fsub_rn(__fadd_rn(__fmul_rn(0.9f, ma), Aa[t]), ra);
        const float rb = (mb > 1.0f) ? 1.0f : 0.0f;
        mb = __fsub_rn(__fadd_rn(__fmul_rn(0.9f, mb), Ab[t]), rb);
        const uint64_t mka = __ballot((int)(ma > 1.0f));
        const uint64_t mkb = __ballot((int)(mb > 1.0f));
        if (lane == 0) {
            uint64_t* dst = &Bout[((long long)t * BATCH + b) * (HTOT / 64) + wbase];
            dst[0] = mka;
            dst[1] = mkb;
        }
    }
}

// ---------------- Output layer (H=10): counts, blocked f32 (kc=280) -------
__global__ __launch_bounds__(256) void layer_out(const uint64_t* __restrict__ S1,
                                                 const float* __restrict__ W2,
                                                 float* __restrict__ out) {
    const int idx = blockIdx.x * blockDim.x + threadIdx.x;
    const int b = idx >> 4;   // 16 threads per batch row (10 used)
    const int o = idx & 15;
    if (b >= BATCH) return;

    float m = 0.0f;
    float cnt = 0.0f;
    for (int t = 0; t < T_STEPS; ++t) {
        float acc = 0.0f;
        float S = 0.0f;
        if (o < OUTF) {
            for (int qw = 0; qw < 64; ++qw) {
                const uint64_t sw = S1[((long long)t * BATCH + b) * 64 + qw];
                const float* wrow = W2 + (long long)o * HID + qw * 64;
#pragma unroll
                for (int fb = 0; fb < 64; ++fb) {
                    S = __fadd_rn(S, ((sw >> fb) & 1ull) ? wrow[fb] : 0.0f);
                    if (((qw * 64 + fb + 1) % KC_L1) == 0) {
                        acc = __fadd_rn(acc, S);
                        S = 0.0f;
                    }
                }
            }
            if (HID % KC_L1 != 0) acc = __fadd_rn(acc, S);
        }
        const float reset = (m > 1.0f) ? 1.0f : 0.0f;
        m = __fsub_rn(__fadd_rn(__fmul_rn(0.9f, m), acc), reset);
        if (m > 1.0f) cnt += 1.0f;
    }
    if (o < OUTF) out[b * OUTF + o] = cnt;
}

// ---------------- Launch ----------------
extern "C" void kernel_launch(void* const* d_in, const int* in_sizes, int n_in,
                              void* d_out, int out_size, void* d_ws, size_t ws_size,
                              hipStream_t stream) {
    const float* x  = (const float*)d_in[0];
    const float* W0 = (const float*)d_in[1];
    const float* W1 = (const float*)d_in[2];
    const float* W2 = (const float*)d_in[3];
    float* out = (float*)d_out;

    char* ws = (char*)d_ws;
    size_t off = 0;
    float* WT0 = (float*)(ws + off); off += (size_t)IN_F * HID * sizeof(float);   // 12.8 MB
    float* WT1 = (float*)(ws + off); off += (size_t)HID * HID * sizeof(float);    // 64 MB
    uint64_t* Sin = (uint64_t*)(ws + off); off += (size_t)T_STEPS * BATCH * 16 * 8; // 3.3 MB
    uint64_t* S0  = (uint64_t*)(ws + off); off += (size_t)T_STEPS * BATCH * 64 * 8; // 13.1 MB
    uint64_t* S1  = (uint64_t*)(ws + off); off += (size_t)T_STEPS * BATCH * 64 * 8; // 13.1 MB
    (void)off; (void)ws_size; (void)in_sizes; (void)n_in; (void)out_size;

    // 1) transpose weights (verified layout)
    {
        long long tot0 = (long long)HID * IN_F;
        transpose_w<<<(int)((tot0 + 255) / 256), 256, 0, stream>>>(W0, WT0, HID, IN_F);
        long long tot1 = (long long)HID * HID;
        transpose_w<<<(int)((tot1 + 255) / 256), 256, 0, stream>>>(W1, WT1, HID, HID);
    }
    // 2) Poisson spike raster via threefry (partitionable, XOR readout)
    gen_spikes<<<(T_STEPS * BATCH) / 4, 256, 0, stream>>>(x, Sin);
    // 3) layer 0: 784 -> 4096, kc=264
    layer_fmac<KC_L0, IN_F, 16, HID, 4>
        <<<BATCH * (HID / 512), 256, 0, stream>>>(Sin, WT0, S0);
    // 4) layer 1: 4096 -> 4096, kc=280
    layer_fmac<KC_L1, HID, 64, HID, 4>
        <<<BATCH * (HID / 512), 256, 0, stream>>>(S0, WT1, S1);
    // 5) layer 2: 4096 -> 10, kc=280, spike counts
    layer_out<<<BATCH * 16 / 256, 256, 0, stream>>>(S1, W2, out);
}

// Round 16
// 19449.382 us; speedup vs baseline: 2.8470x; 1.0775x over previous
//
#include <hip/hip_runtime.h>
#include <stdint.h>

#define T_STEPS 25
#define BATCH   1024
#define IN_F    784
#define HID     4096
#define OUTF    10
// Eigen SINGLE-THREADED gebp blocking (verified bit-exact R11/R12/R14/R15):
// max_kc=288 evened -> kc(784)=264 (264+264+256), kc(4096)=280 (14x280+176).
#define KC_L0   264
#define KC_L1   280

typedef float v2f __attribute__((ext_vector_type(2)));

// ---------------- Threefry-2x32, key = (0, 42), 20 rounds ----------------
__device__ __forceinline__ uint32_t rotl32(uint32_t x, int d) {
    return (x << d) | (x >> (32 - d));
}

__device__ __forceinline__ void threefry2x32_42(uint32_t x0, uint32_t x1,
                                                uint32_t& r0, uint32_t& r1) {
    const uint32_t k0 = 0u, k1 = 42u;
    const uint32_t k2 = k0 ^ k1 ^ 0x1BD11BDAu;
    x0 += k0; x1 += k1;
#define TF_ROUND(r) { x0 += x1; x1 = rotl32(x1, r); x1 ^= x0; }
    TF_ROUND(13) TF_ROUND(15) TF_ROUND(26) TF_ROUND(6)
    x0 += k1; x1 += k2 + 1u;
    TF_ROUND(17) TF_ROUND(29) TF_ROUND(16) TF_ROUND(24)
    x0 += k2; x1 += k0 + 2u;
    TF_ROUND(13) TF_ROUND(15) TF_ROUND(26) TF_ROUND(6)
    x0 += k0; x1 += k1 + 3u;
    TF_ROUND(17) TF_ROUND(29) TF_ROUND(16) TF_ROUND(24)
    x0 += k1; x1 += k2 + 4u;
    TF_ROUND(13) TF_ROUND(15) TF_ROUND(26) TF_ROUND(6)
    x0 += k2; x1 += k0 + 5u;
#undef TF_ROUND
    r0 = x0; r1 = x1;
}

// ---------------- Input spike generation (bitmask, ballot) ----------------
__global__ __launch_bounds__(256) void gen_spikes(const float* __restrict__ x,
                                                  uint64_t* __restrict__ Sin) {
    const int lane = threadIdx.x & 63;
    const int wid  = __builtin_amdgcn_readfirstlane(blockIdx.x * 4 + (threadIdx.x >> 6));
    if (wid >= T_STEPS * BATCH) return;
    const int b = wid % BATCH;

    for (int qw = 0; qw < 16; ++qw) {
        bool pred = false;
        const int f = qw * 64 + lane;
        if (f < IN_F) {
            const uint32_t i = (uint32_t)(wid * IN_F + f);
            uint32_t r0, r1;
            threefry2x32_42(0u, i, r0, r1);
            const uint32_t bits = r0 ^ r1;
            const uint32_t fbits = (bits >> 9) | 0x3f800000u;
            const float u = __uint_as_float(fbits) - 1.0f;
            float p = x[b * IN_F + f];
            p = fminf(fmaxf(p, 0.0f), 1.0f);
            pred = (u < p);
        }
        const uint64_t mask = __ballot((int)pred);
        if (lane == 0) Sin[(long long)wid * 16 + qw] = mask;
    }
}

// ---------------- Weight transpose: WT[f*H + h] = W[h*F + f] ----------------
__global__ __launch_bounds__(256) void transpose_w(const float* __restrict__ W,
                                                   float* __restrict__ WT,
                                                   int H, int F) {
    const long long idx = (long long)blockIdx.x * blockDim.x + threadIdx.x;
    const long long tot = (long long)H * F;
    if (idx >= tot) return;
    const long long f = idx / H;
    const long long h = idx % H;
    WT[idx] = W[h * (long long)F + f];
}

// ---------------- Fused layer: 2 h-cols/thread, packed-f32 MACs -----------
// Bit-exact to Eigen gebp (verified): S += fbit*w per k ascending, folds at
// global k % KCB == 0, tail fold. v_pk_fma_f32 pairs adjacent timesteps —
// per-component IEEE rounding identical to scalar fmaf, so arithmetic is
// unchanged. Tile reads stay 6 x ds_read_b128 + 1 x ds_read_b32 per k.
template<int KCB, int KTOT, int IN_STRIDE, int HTOT, int WPB>
__global__ __launch_bounds__(WPB * 64, 4) void layer_fmac(
    const uint64_t* __restrict__ Bin,   // [T][B][IN_STRIDE] u64, bit index = k
    const float*    __restrict__ WT,    // [KTOT][HTOT]
    uint64_t*       __restrict__ Bout)  // [T][B][HTOT/64]
{
    __shared__ alignas(16) float tile[256 * 28];    // 28 KB
    const int tid  = threadIdx.x;
    const int lane = tid & 63;
    const int wv   = tid >> 6;
    const int nhb  = HTOT / (WPB * 128);            // 128 h per wave
    const int b    = blockIdx.x / nhb;
    const int hb   = blockIdx.x % nhb;              // == XCD id when nhb==8
    const int ha   = hb * (WPB * 128) + wv * 128 + lane;
    const int hc   = ha + 64;

    v2f  SA[12], SB[12], AA[12], AB[12];
    float SA24, SB24, AA24, AB24;
#pragma unroll
    for (int j = 0; j < 12; ++j) {
        SA[j] = (v2f)0.0f; SB[j] = (v2f)0.0f;
        AA[j] = (v2f)0.0f; AB[j] = (v2f)0.0f;
    }
    SA24 = SB24 = AA24 = AB24 = 0.0f;

    int nf = KCB;                       // next fold boundary (k+1 == nf)
    const int NCH = (KTOT + 255) / 256;
    for (int c = 0; c < NCH; ++c) {
        const int k0 = c * 256;
        const int kv = (KTOT - k0 < 256) ? (KTOT - k0) : 256;
        __syncthreads();                // previous tile fully consumed
        const int NV = kv * T_STEPS;
        for (int r = 0; r < (NV + WPB * 64 - 1) / (WPB * 64); ++r) {
            const int idx = r * (WPB * 64) + tid;
            if (idx < NV) {
                const int kk = (idx * 5243) >> 17;   // idx/25, exact < 43690
                const int t  = idx - kk * 25;
                const int k  = k0 + kk;
                const uint64_t word =
                    Bin[((long long)t * BATCH + b) * IN_STRIDE + (k >> 6)];
                tile[kk * 28 + t] = ((word >> (k & 63)) & 1ull) ? 1.0f : 0.0f;
            }
        }
        __syncthreads();

        float wa = WT[(long long)k0 * HTOT + ha];
        float wb = WT[(long long)k0 * HTOT + hc];
        for (int kk = 0; kk < kv; ++kk) {
            const int kn = (kk + 1 < kv) ? kk + 1 : kv - 1;   // clamped prefetch
            const float wan = WT[(long long)(k0 + kn) * HTOT + ha];
            const float wbn = WT[(long long)(k0 + kn) * HTOT + hc];
            const float* fb = &tile[kk * 28];
            v2f wa2; wa2.x = wa; wa2.y = wa;
            v2f wb2; wb2.x = wb; wb2.y = wb;
#pragma unroll
            for (int q = 0; q < 6; ++q) {           // 6 x ds_read_b128
                const float4 f = *(const float4*)(fb + 4 * q);
                v2f plo; plo.x = f.x; plo.y = f.y;
                v2f phi; phi.x = f.z; phi.y = f.w;
                SA[2*q]   = __builtin_elementwise_fma(plo, wa2, SA[2*q]);
                SA[2*q+1] = __builtin_elementwise_fma(phi, wa2, SA[2*q+1]);
                SB[2*q]   = __builtin_elementwise_fma(plo, wb2, SB[2*q]);
                SB[2*q+1] = __builtin_elementwise_fma(phi, wb2, SB[2*q+1]);
            }
            {   const float f24 = fb[24];
                SA24 = fmaf(f24, wa, SA24);
                SB24 = fmaf(f24, wb, SB24); }
            if (k0 + kk + 1 == nf) {                // exact KC fold boundary
#pragma unroll
                for (int j = 0; j < 12; ++j) {
                    AA[j] = AA[j] + SA[j];  SA[j] = (v2f)0.0f;
                    AB[j] = AB[j] + SB[j];  SB[j] = (v2f)0.0f;
                }
                AA24 = __fadd_rn(AA24, SA24);  SA24 = 0.0f;
                AB24 = __fadd_rn(AB24, SB24);  SB24 = 0.0f;
                nf += KCB;
            }
            wa = wan; wb = wbn;
        }
    }
    if (KTOT % KCB != 0) {
#pragma unroll
        for (int j = 0; j < 12; ++j) {
            AA[j] = AA[j] + SA[j];
            AB[j] = AB[j] + SB[j];
        }
        AA24 = __fadd_rn(AA24, SA24);
        AB24 = __fadd_rn(AB24, SB24);
    }

    // LIF recursion x2, strict f32 separate roundings (verified R11)
    float ma = 0.0f, mb = 0.0f;
    const long long wbase = hb * (WPB * 2) + wv * 2;
#pragma unroll
    for (int t = 0; t < T_STEPS; ++t) {
        const float ca = (t == 24) ? AA24 : ((t & 1) ? AA[t >> 1].y : AA[t >> 1].x);
        const float cb = (t == 24) ? AB24 : ((t & 1) ? AB[t >> 1].y : AB[t >> 1].x);
        const float ra = (ma > 1.0f) ? 1.0f : 0.0f;
        ma = __fsub_rn(__fadd_rn(__fmul_rn(0.9f, ma), ca), ra);
        const float rb = (mb > 1.0f) ? 1.0f : 0.0f;
        mb = __fsub_rn(__fadd_rn(__fmul_rn(0.9f, mb), cb), rb);
        const uint64_t mka = __ballot((int)(ma > 1.0f));
        const uint64_t mkb = __ballot((int)(mb > 1.0f));
        if (lane == 0) {
            uint64_t* dst = &Bout[((long long)t * BATCH + b) * (HTOT / 64) + wbase];
            dst[0] = mka;
            dst[1] = mkb;
        }
    }
}

// ---------------- Output layer (H=10): counts, blocked f32 (kc=280) -------
__global__ __launch_bounds__(256) void layer_out(const uint64_t* __restrict__ S1,
                                                 const float* __restrict__ W2,
                                                 float* __restrict__ out) {
    const int idx = blockIdx.x * blockDim.x + threadIdx.x;
    const int b = idx >> 4;   // 16 threads per batch row (10 used)
    const int o = idx & 15;
    if (b >= BATCH) return;

    float m = 0.0f;
    float cnt = 0.0f;
    for (int t = 0; t < T_STEPS; ++t) {
        float acc = 0.0f;
        float S = 0.0f;
        if (o < OUTF) {
            for (int qw = 0; qw < 64; ++qw) {
                const uint64_t sw = S1[((long long)t * BATCH + b) * 64 + qw];
                const float* wrow = W2 + (long long)o * HID + qw * 64;
#pragma unroll
                for (int fb = 0; fb < 64; ++fb) {
                    S = __fadd_rn(S, ((sw >> fb) & 1ull) ? wrow[fb] : 0.0f);
                    if (((qw * 64 + fb + 1) % KC_L1) == 0) {
                        acc = __fadd_rn(acc, S);
                        S = 0.0f;
                    }
                }
            }
            if (HID % KC_L1 != 0) acc = __fadd_rn(acc, S);
        }
        const float reset = (m > 1.0f) ? 1.0f : 0.0f;
        m = __fsub_rn(__fadd_rn(__fmul_rn(0.9f, m), acc), reset);
        if (m > 1.0f) cnt += 1.0f;
    }
    if (o < OUTF) out[b * OUTF + o] = cnt;
}

// ---------------- Launch ----------------
extern "C" void kernel_launch(void* const* d_in, const int* in_sizes, int n_in,
                              void* d_out, int out_size, void* d_ws, size_t ws_size,
                              hipStream_t stream) {
    const float* x  = (const float*)d_in[0];
    const float* W0 = (const float*)d_in[1];
    const float* W1 = (const float*)d_in[2];
    const float* W2 = (const float*)d_in[3];
    float* out = (float*)d_out;

    char* ws = (char*)d_ws;
    size_t off = 0;
    float* WT0 = (float*)(ws + off); off += (size_t)IN_F * HID * sizeof(float);   // 12.8 MB
    float* WT1 = (float*)(ws + off); off += (size_t)HID * HID * sizeof(float);    // 64 MB
    uint64_t* Sin = (uint64_t*)(ws + off); off += (size_t)T_STEPS * BATCH * 16 * 8; // 3.3 MB
    uint64_t* S0  = (uint64_t*)(ws + off); off += (size_t)T_STEPS * BATCH * 64 * 8; // 13.1 MB
    uint64_t* S1  = (uint64_t*)(ws + off); off += (size_t)T_STEPS * BATCH * 64 * 8; // 13.1 MB
    (void)off; (void)ws_size; (void)in_sizes; (void)n_in; (void)out_size;

    // 1) transpose weights (verified layout)
    {
        long long tot0 = (long long)HID * IN_F;
        transpose_w<<<(int)((tot0 + 255) / 256), 256, 0, stream>>>(W0, WT0, HID, IN_F);
        long long tot1 = (long long)HID * HID;
        transpose_w<<<(int)((tot1 + 255) / 256), 256, 0, stream>>>(W1, WT1, HID, HID);
    }
    // 2) Poisson spike raster via threefry (partitionable, XOR readout)
    gen_spikes<<<(T_STEPS * BATCH) / 4, 256, 0, stream>>>(x, Sin);
    // 3) layer 0: 784 -> 4096, kc=264
    layer_fmac<KC_L0, IN_F, 16, HID, 4>
        <<<BATCH * (HID / 512), 256, 0, stream>>>(Sin, WT0, S0);
    // 4) layer 1: 4096 -> 4096, kc=280
    layer_fmac<KC_L1, HID, 64, HID, 4>
        <<<BATCH * (HID / 512), 256, 0, stream>>>(S0, WT1, S1);
    // 5) layer 2: 4096 -> 10, kc=280, spike counts
    layer_out<<<BATCH * 16 / 256, 256, 0, stream>>>(S1, W2, out);
}